// Round 3
// baseline (58.512 us; speedup 1.0000x reference)
//
#include <hip/hip_runtime.h>
#include <hip/hip_bf16.h>

// Problem constants
#define B_   2
#define T_   2
#define H_   56
#define W_   56
#define C_   256
#define NH_  8
#define HD_  32
#define NWW_ 14      // windows along W (W_sp=4)
#define TQ_  448     // queries per window = T*56*4
#define SEQ_ 576     // staged K/V tokens: 448 window + 112 pooled + 16 zero pad
#define REAL_ 560
#define VIRT_ 320.0f // remaining zero-logit pooled tokens folded analytically
#define MEXP_ 16.0f  // fixed softmax max (exp2 domain); realized |logit*log2e| < ~10

typedef __bf16 bf16;
typedef __bf16 bf16x8 __attribute__((ext_vector_type(8)));
typedef __bf16 bf16x4 __attribute__((ext_vector_type(4)));
typedef float  f32x4  __attribute__((ext_vector_type(4)));
typedef short  s16x4  __attribute__((ext_vector_type(4)));
typedef unsigned int  uint;
typedef uint   uint4v __attribute__((ext_vector_type(4)));
typedef uint   uint2v __attribute__((ext_vector_type(2)));
typedef unsigned short u16;

#if defined(__has_builtin)
#  if __has_builtin(__builtin_amdgcn_mfma_f32_16x16x16bf16_1k)
#    define USE_MFMA16 1
#  endif
#endif
#ifndef USE_MFMA16
#  define USE_MFMA16 0
#endif

__device__ __forceinline__ uint pack2(float a, float b) {
    u16 ha = __builtin_bit_cast(u16, (bf16)a);
    u16 hb = __builtin_bit_cast(u16, (bf16)b);
    return (uint)ha | ((uint)hb << 16);
}

// ---------------------------------------------------------------------------
// Kernel 1: pooled maps. grid = (b,t,j,quarter) = 224 blocks, 256 threads (c).
// Each block accumulates 56 of the 224 window rows for all 4 pooled slots and
// atomically adds partials into pm_k/pm_v (zeroed by hipMemsetAsync).
// ---------------------------------------------------------------------------
__global__ void pool_kernel(const float* __restrict__ k_in, const float* __restrict__ v_in,
                            const float* __restrict__ pool_w, const float* __restrict__ pool_b,
                            float* __restrict__ pm_k, float* __restrict__ pm_v) {
    __shared__ float pws[4][56];
    const int quarter = blockIdx.x & 3;
    const int bj = blockIdx.x >> 2;
    const int j  = bj % NWW_;
    const int t  = (bj / NWW_) % T_;
    const int b  = bj / (NWW_ * T_);
    const int c  = threadIdx.x;
    const int n0 = quarter * 56;

    if (c < 224) pws[c / 56][c % 56] = pool_w[(c / 56) * 224 + n0 + (c % 56)];
    __syncthreads();

    float ak[4], av[4];
    #pragma unroll
    for (int s = 0; s < 4; ++s) {
        ak[s] = (quarter == 0) ? pool_b[s] : 0.f;
        av[s] = 0.f;
    }
    for (int i = 0; i < 56; ++i) {
        const int n = n0 + i;
        const int h = n >> 2, wi = n & 3;
        const size_t off = ((size_t)(((b * T_ + t) * H_ + h) * W_ + (j * 4 + wi))) * C_ + c;
        const float kv = k_in[off];
        const float vv = v_in[off];
        #pragma unroll
        for (int s = 0; s < 4; ++s) {
            ak[s] += kv * pws[s][i];
            av[s] += vv * pws[s][i];
        }
    }
    #pragma unroll
    for (int s = 0; s < 4; ++s) {
        const size_t o = ((size_t)(((b * T_ + t) * 4 + s) * NWW_ + j)) * C_ + c;
        atomicAdd(&pm_k[o], ak[s]);
        atomicAdd(&pm_v[o], av[s]);
    }
}

// ---------------------------------------------------------------------------
// Kernel 2: depthwise 3x3 LePE conv within each 56x4 strip ('SAME' zero pad).
// grid = (bt, h) = 224 blocks, 256 threads (c). Register-tiled 3x4 taps/strip.
// ---------------------------------------------------------------------------
__global__ void lepe_kernel(const float* __restrict__ v_in, const float* __restrict__ gw,
                            const float* __restrict__ gb, bf16* __restrict__ lepe) {
    const int c  = threadIdx.x;
    const int h  = blockIdx.x % H_;
    const int bt = blockIdx.x / H_;

    float wv[9];
    #pragma unroll
    for (int k = 0; k < 9; ++k) wv[k] = gw[c * 9 + k];
    const float bias = gb[c];

    for (int strip = 0; strip < NWW_; ++strip) {
        float tile[3][4];
        #pragma unroll
        for (int dy = 0; dy < 3; ++dy) {
            const int hh = h - 1 + dy;
            const bool ok = (hh >= 0 && hh < H_);
            #pragma unroll
            for (int x = 0; x < 4; ++x) {
                tile[dy][x] = ok
                    ? v_in[((size_t)(bt * H_ + hh) * W_ + (strip * 4 + x)) * C_ + c]
                    : 0.f;
            }
        }
        #pragma unroll
        for (int wi = 0; wi < 4; ++wi) {
            float acc = bias;
            #pragma unroll
            for (int dy = 0; dy < 3; ++dy) {
                #pragma unroll
                for (int dx = -1; dx <= 1; ++dx) {
                    const int xx = wi + dx;
                    if (xx >= 0 && xx < 4)
                        acc += wv[dy * 3 + dx + 1] * tile[dy][xx];
                }
            }
            lepe[((size_t)(bt * H_ + h) * W_ + (strip * 4 + wi)) * C_ + c] = (bf16)acc;
        }
    }
}

// ---------------------------------------------------------------------------
// Kernel 3: windowed attention. Fixed softmax max (exp2 domain), lane-local
// softmax+PV (no cross-lane traffic after staging). 320 virtual zero-logit
// tokens folded into the denominator. LePE added in epilogue.
// grid = NW*NH = 224 blocks, 256 threads (4 waves x 112 q-rows)
// ---------------------------------------------------------------------------
__launch_bounds__(256, 1)
__global__ void attn_kernel(const float* __restrict__ q_in, const float* __restrict__ k_in,
                            const float* __restrict__ v_in, const float* __restrict__ pm_k,
                            const float* __restrict__ pm_v, const bf16* __restrict__ lepe,
                            float* __restrict__ out) {
    // K row-major [tok][hd], row stride 40 ushorts (80B)
    __shared__ __align__(16) u16 Ks[SEQ_ * 40];
    // V transposed [hd][tok], row stride 584 ushorts (1168B)
    __shared__ __align__(16) u16 Vt[32 * 584];

    const int tid  = threadIdx.x;
    const int nh   = blockIdx.x & 7;
    const int nwi  = blockIdx.x >> 3;
    const int b    = nwi / NWW_;
    const int ww   = nwi % NWW_;
    const int cbase = nh * 32;

    // ---- stage K (row-major, padded) and V (transposed) into LDS ----
    for (int idx = tid; idx < SEQ_ * 4; idx += 256) {
        const int tok = idx >> 2, slot = idx & 3;
        uint4v dk = {0, 0, 0, 0}, dv = {0, 0, 0, 0};
        if (tok < TQ_) {
            const int t = tok / 224, r = tok % 224;
            const int h = r >> 2, wi = r & 3;
            const size_t off =
                ((size_t)(((b * T_ + t) * H_ + h) * W_ + (ww * 4 + wi))) * C_ + cbase + slot * 8;
            const f32x4 k0 = *(const f32x4*)(k_in + off);
            const f32x4 k1 = *(const f32x4*)(k_in + off + 4);
            const f32x4 v0 = *(const f32x4*)(v_in + off);
            const f32x4 v1 = *(const f32x4*)(v_in + off + 4);
            dk = uint4v{pack2(k0[0], k0[1]), pack2(k0[2], k0[3]),
                        pack2(k1[0], k1[1]), pack2(k1[2], k1[3])};
            dv = uint4v{pack2(v0[0], v0[1]), pack2(v0[2], v0[3]),
                        pack2(v1[0], v1[1]), pack2(v1[2], v1[3])};
        } else if (tok < REAL_) {
            const int i = tok - TQ_;
            const int t = i / 56, r = i % 56;
            const int kh = r / 14, jj = r % 14;
            const size_t off =
                ((size_t)(((b * T_ + t) * 4 + kh) * NWW_ + jj)) * C_ + cbase + slot * 8;
            const float* pk = pm_k + off;
            const float* pv = pm_v + off;
            dk = uint4v{pack2(pk[0], pk[1]), pack2(pk[2], pk[3]),
                        pack2(pk[4], pk[5]), pack2(pk[6], pk[7])};
            dv = uint4v{pack2(pv[0], pv[1]), pack2(pv[2], pv[3]),
                        pack2(pv[4], pv[5]), pack2(pv[6], pv[7])};
        }
        *(uint4v*)(Ks + tok * 40 + slot * 8) = dk;
        u16 es[8];
        #pragma unroll
        for (int e = 0; e < 8; ++e) es[e] = (u16)((dv[e >> 1] >> ((e & 1) * 16)) & 0xffff);
        #pragma unroll
        for (int e = 0; e < 8; ++e) Vt[(slot * 8 + e) * 584 + tok] = es[e];
    }
    __syncthreads();

    const int lane = tid & 63;
    const int wv   = tid >> 6;
    const int l15  = lane & 15;
    const int g    = lane >> 4;
    const float QS = 0.17677669529663687f * 1.4426950408889634f; // HD^-0.5 * log2(e)

    // ---- Q fragments (7 tiles of 16 rows per wave), scaled into exp2 domain ----
    bf16x8 qf[7];
    #pragma unroll
    for (int qt = 0; qt < 7; ++qt) {
        const int qrow = wv * 112 + qt * 16 + l15;
        const int t = qrow / 224, r = qrow % 224;
        const int h = r >> 2, wi = r & 3;
        const size_t off =
            ((size_t)(((b * T_ + t) * H_ + h) * W_ + (ww * 4 + wi))) * C_ + cbase + g * 8;
        const f32x4 a0 = *(const f32x4*)(q_in + off);
        const f32x4 a1 = *(const f32x4*)(q_in + off + 4);
        const uint4v qp = {pack2(a0[0] * QS, a0[1] * QS), pack2(a0[2] * QS, a0[3] * QS),
                           pack2(a1[0] * QS, a1[1] * QS), pack2(a1[2] * QS, a1[3] * QS)};
        qf[qt] = __builtin_bit_cast(bf16x8, qp);
    }

    f32x4 o[7][2];
    float ssum[7];
    const f32x4 zf = {0.f, 0.f, 0.f, 0.f};
    #pragma unroll
    for (int qt = 0; qt < 7; ++qt) {
        o[qt][0] = zf; o[qt][1] = zf; ssum[qt] = 0.f;
    }

    // ---- loop over 18 chunks of 32 tokens ----
    for (int kc = 0; kc < SEQ_ / 32; ++kc) {
        const int kt0 = kc * 32;
        const bf16x8 ka = *(const bf16x8*)(Ks + (kt0 + l15) * 40 + g * 8);
        const bf16x8 kb = *(const bf16x8*)(Ks + (kt0 + 16 + l15) * 40 + g * 8);
#if USE_MFMA16
        // V^T A-fragments for 16x16x16 PV: lane(l15,g) row=l15(+16*h2), k=g*4+e
        const s16x4 va00 = __builtin_bit_cast(s16x4, *(const uint2v*)(Vt + l15 * 584 + kt0 + g * 4));
        const s16x4 va01 = __builtin_bit_cast(s16x4, *(const uint2v*)(Vt + l15 * 584 + kt0 + 16 + g * 4));
        const s16x4 va10 = __builtin_bit_cast(s16x4, *(const uint2v*)(Vt + (16 + l15) * 584 + kt0 + g * 4));
        const s16x4 va11 = __builtin_bit_cast(s16x4, *(const uint2v*)(Vt + (16 + l15) * 584 + kt0 + 16 + g * 4));
#else
        const bf16x8 va = *(const bf16x8*)(Vt + l15 * 584 + kt0 + g * 8);
        const bf16x8 vb = *(const bf16x8*)(Vt + (16 + l15) * 584 + kt0 + g * 8);
#endif

        #pragma unroll
        for (int qt = 0; qt < 7; ++qt) {
            // S^T tiles: lane holds scores for q = l15, ktok = kt0 + (tile*16 + g*4 + r)
            const f32x4 s0 = __builtin_amdgcn_mfma_f32_16x16x32_bf16(ka, qf[qt], zf, 0, 0, 0);
            const f32x4 s1 = __builtin_amdgcn_mfma_f32_16x16x32_bf16(kb, qf[qt], zf, 0, 0, 0);

            const float p0 = __builtin_amdgcn_exp2f(s0[0] - MEXP_);
            const float p1 = __builtin_amdgcn_exp2f(s0[1] - MEXP_);
            const float p2 = __builtin_amdgcn_exp2f(s0[2] - MEXP_);
            const float p3 = __builtin_amdgcn_exp2f(s0[3] - MEXP_);
            const float p4 = __builtin_amdgcn_exp2f(s1[0] - MEXP_);
            const float p5 = __builtin_amdgcn_exp2f(s1[1] - MEXP_);
            const float p6 = __builtin_amdgcn_exp2f(s1[2] - MEXP_);
            const float p7 = __builtin_amdgcn_exp2f(s1[3] - MEXP_);

            ssum[qt] += ((p0 + p1) + (p2 + p3)) + ((p4 + p5) + (p6 + p7));

            const uint w0 = pack2(p0, p1), w1 = pack2(p2, p3);
            const uint w2 = pack2(p4, p5), w3 = pack2(p6, p7);
#if USE_MFMA16
            // B-operand of 16x16x16 == S^T layout: col=l15=q, k=g*4+r. Lane-local.
            const s16x4 pb0 = __builtin_bit_cast(s16x4, uint2v{w0, w1});
            const s16x4 pb1 = __builtin_bit_cast(s16x4, uint2v{w2, w3});
            o[qt][0] = __builtin_amdgcn_mfma_f32_16x16x16bf16_1k(va00, pb0, o[qt][0], 0, 0, 0);
            o[qt][0] = __builtin_amdgcn_mfma_f32_16x16x16bf16_1k(va01, pb1, o[qt][0], 0, 0, 0);
            o[qt][1] = __builtin_amdgcn_mfma_f32_16x16x16bf16_1k(va10, pb0, o[qt][1], 0, 0, 0);
            o[qt][1] = __builtin_amdgcn_mfma_f32_16x16x16bf16_1k(va11, pb1, o[qt][1], 0, 0, 0);
#else
            // rearrange P to 16x16x32 A-fragment in-register (race-free shuffles)
            const int baseln = l15 + ((g & 1) << 5);
            const uint sA = (g & 2) ? w2 : w0;
            const uint sB = (g & 2) ? w3 : w1;
            const uint o0 = (uint)__shfl((int)sA, baseln);
            const uint o1 = (uint)__shfl((int)sB, baseln);
            const uint o2 = (uint)__shfl((int)sA, baseln + 16);
            const uint o3 = (uint)__shfl((int)sB, baseln + 16);
            const bf16x8 pf = __builtin_bit_cast(bf16x8, uint4v{o0, o1, o2, o3});
            o[qt][0] = __builtin_amdgcn_mfma_f32_16x16x32_bf16(pf, va, o[qt][0], 0, 0, 0);
            o[qt][1] = __builtin_amdgcn_mfma_f32_16x16x32_bf16(pf, vb, o[qt][1], 0, 0, 0);
#endif
        }
    }

    // ---- epilogue: reduce denominator across g, add virtual zeros, LePE, store ----
    #pragma unroll
    for (int qt = 0; qt < 7; ++qt) {
        float den = ssum[qt];
        den += __shfl_xor(den, 16);
        den += __shfl_xor(den, 32);
        den += VIRT_ * 0.0000152587890625f; // 320 * 2^-16
        const float osc = 1.0f / den;       // valid in every lane, for q = l15

#if USE_MFMA16
        // o[qt][h2] reg r = O[q=l15][cbase + h2*16 + g*4 + r] — fully lane-local
        const int qrow = wv * 112 + qt * 16 + l15;
        const int t = qrow / 224, rr = qrow % 224;
        const int h = rr >> 2, wi = rr & 3;
        const size_t off =
            ((size_t)(((b * T_ + t) * H_ + h) * W_ + (ww * 4 + wi))) * C_ + cbase;
        #pragma unroll
        for (int h2 = 0; h2 < 2; ++h2) {
            const int co = h2 * 16 + g * 4;
            const bf16x4 lp = *(const bf16x4*)(lepe + off + co);
            f32x4 val;
            #pragma unroll
            for (int r = 0; r < 4; ++r) val[r] = o[qt][h2][r] * osc + (float)lp[r];
            *(f32x4*)(out + off + co) = val;
        }
#else
        // o[qt][j] reg r = O[q = g*4+r][hd = l15 + 16*j]
        #pragma unroll
        for (int r = 0; r < 4; ++r) {
            const float oscr = __shfl(osc, g * 4 + r);
            const int qrow = wv * 112 + qt * 16 + g * 4 + r;
            const int t = qrow / 224, rr = qrow % 224;
            const int h = rr >> 2, wi = rr & 3;
            const size_t off =
                ((size_t)(((b * T_ + t) * H_ + h) * W_ + (ww * 4 + wi))) * C_ + cbase + l15;
            out[off]      = o[qt][0][r] * oscr + (float)lepe[off];
            out[off + 16] = o[qt][1][r] * oscr + (float)lepe[off + 16];
        }
#endif
    }
}

// ---------------------------------------------------------------------------
extern "C" void kernel_launch(void* const* d_in, const int* in_sizes, int n_in,
                              void* d_out, int out_size, void* d_ws, size_t ws_size,
                              hipStream_t stream) {
    const float* qkv = (const float*)d_in[0];
    const float* gw  = (const float*)d_in[1];
    const float* gb  = (const float*)d_in[2];
    const float* pw  = (const float*)d_in[3];
    const float* pb  = (const float*)d_in[4];

    const size_t plane = (size_t)B_ * T_ * H_ * W_ * C_; // 3,211,264
    const float* q_in = qkv;
    const float* k_in = qkv + plane;
    const float* v_in = qkv + 2 * plane;

    const size_t pm_elems = (size_t)B_ * T_ * 4 * NWW_ * C_; // 57,344
    float* pm_k = (float*)d_ws;
    float* pm_v = pm_k + pm_elems;
    bf16*  lepe = (bf16*)(pm_v + pm_elems);
    float* outp = (float*)d_out;

    hipMemsetAsync(d_ws, 0, 2 * pm_elems * sizeof(float), stream);
    hipLaunchKernelGGL(pool_kernel, dim3(B_ * T_ * NWW_ * 4), dim3(256), 0, stream,
                       k_in, v_in, pw, pb, pm_k, pm_v);
    hipLaunchKernelGGL(lepe_kernel, dim3(B_ * T_ * H_), dim3(256), 0, stream,
                       v_in, gw, gb, lepe);
    hipLaunchKernelGGL(attn_kernel, dim3(28 * 8), dim3(256), 0, stream,
                       q_in, k_in, v_in, pm_k, pm_v, lepe, outp);
}

// Round 4
// 58.044 us; speedup vs baseline: 1.0081x; 1.0081x over previous
//
#include <hip/hip_runtime.h>
#include <hip/hip_bf16.h>

// Problem constants
#define B_   2
#define T_   2
#define H_   56
#define W_   56
#define C_   256
#define NH_  8
#define HD_  32
#define NWW_ 14      // windows along W (W_sp=4)
#define TQ_  448     // queries per window = T*56*4
#define SEQ_ 576     // staged K/V tokens: 448 window + 112 pooled + 16 zero pad
#define REAL_ 560
#define VIRT_ 320.0f // remaining zero-logit pooled tokens folded analytically
#define MEXP_ 16.0f  // fixed softmax max (exp2 domain); realized |logit*log2e| < ~10

typedef __bf16 bf16;
typedef __bf16 bf16x8 __attribute__((ext_vector_type(8)));
typedef __bf16 bf16x4 __attribute__((ext_vector_type(4)));
typedef float  f32x4  __attribute__((ext_vector_type(4)));
typedef short  s16x4  __attribute__((ext_vector_type(4)));
typedef unsigned int  uint;
typedef uint   uint4v __attribute__((ext_vector_type(4)));
typedef uint   uint2v __attribute__((ext_vector_type(2)));
typedef unsigned short u16;

#if defined(__has_builtin)
#  if __has_builtin(__builtin_amdgcn_mfma_f32_16x16x16bf16_1k)
#    define USE_MFMA16 1
#  endif
#endif
#ifndef USE_MFMA16
#  define USE_MFMA16 0
#endif

__device__ __forceinline__ uint pack2(float a, float b) {
    u16 ha = __builtin_bit_cast(u16, (bf16)a);
    u16 hb = __builtin_bit_cast(u16, (bf16)b);
    return (uint)ha | ((uint)hb << 16);
}

// ---------------------------------------------------------------------------
// Kernel 1: pooled maps. grid = (b,t,j,quarter) = 224 blocks, 256 threads (c).
// Each block accumulates 56 of the 224 window rows for all 4 pooled slots and
// atomically adds partials into pm_k/pm_v (zeroed by hipMemsetAsync).
// ---------------------------------------------------------------------------
__global__ void pool_kernel(const float* __restrict__ k_in, const float* __restrict__ v_in,
                            const float* __restrict__ pool_w, const float* __restrict__ pool_b,
                            float* __restrict__ pm_k, float* __restrict__ pm_v) {
    __shared__ float pws[4][56];
    const int quarter = blockIdx.x & 3;
    const int bj = blockIdx.x >> 2;
    const int j  = bj % NWW_;
    const int t  = (bj / NWW_) % T_;
    const int b  = bj / (NWW_ * T_);
    const int c  = threadIdx.x;
    const int n0 = quarter * 56;

    if (c < 224) pws[c / 56][c % 56] = pool_w[(c / 56) * 224 + n0 + (c % 56)];
    __syncthreads();

    float ak[4], av[4];
    #pragma unroll
    for (int s = 0; s < 4; ++s) {
        ak[s] = (quarter == 0) ? pool_b[s] : 0.f;
        av[s] = 0.f;
    }
    for (int i = 0; i < 56; ++i) {
        const int n = n0 + i;
        const int h = n >> 2, wi = n & 3;
        const size_t off = ((size_t)(((b * T_ + t) * H_ + h) * W_ + (j * 4 + wi))) * C_ + c;
        const float kv = k_in[off];
        const float vv = v_in[off];
        #pragma unroll
        for (int s = 0; s < 4; ++s) {
            ak[s] += kv * pws[s][i];
            av[s] += vv * pws[s][i];
        }
    }
    #pragma unroll
    for (int s = 0; s < 4; ++s) {
        const size_t o = ((size_t)(((b * T_ + t) * 4 + s) * NWW_ + j)) * C_ + c;
        atomicAdd(&pm_k[o], ak[s]);
        atomicAdd(&pm_v[o], av[s]);
    }
}

// ---------------------------------------------------------------------------
// Kernel 2: depthwise 3x3 LePE conv within each 56x4 strip ('SAME' zero pad).
// grid = (bt, h) = 224 blocks, 256 threads (c). Register-tiled 3x4 taps/strip.
// ---------------------------------------------------------------------------
__global__ void lepe_kernel(const float* __restrict__ v_in, const float* __restrict__ gw,
                            const float* __restrict__ gb, bf16* __restrict__ lepe) {
    const int c  = threadIdx.x;
    const int h  = blockIdx.x % H_;
    const int bt = blockIdx.x / H_;

    float wv[9];
    #pragma unroll
    for (int k = 0; k < 9; ++k) wv[k] = gw[c * 9 + k];
    const float bias = gb[c];

    for (int strip = 0; strip < NWW_; ++strip) {
        float tile[3][4];
        #pragma unroll
        for (int dy = 0; dy < 3; ++dy) {
            const int hh = h - 1 + dy;
            const bool ok = (hh >= 0 && hh < H_);
            #pragma unroll
            for (int x = 0; x < 4; ++x) {
                tile[dy][x] = ok
                    ? v_in[((size_t)(bt * H_ + hh) * W_ + (strip * 4 + x)) * C_ + c]
                    : 0.f;
            }
        }
        #pragma unroll
        for (int wi = 0; wi < 4; ++wi) {
            float acc = bias;
            #pragma unroll
            for (int dy = 0; dy < 3; ++dy) {
                #pragma unroll
                for (int dx = -1; dx <= 1; ++dx) {
                    const int xx = wi + dx;
                    if (xx >= 0 && xx < 4)
                        acc += wv[dy * 3 + dx + 1] * tile[dy][xx];
                }
            }
            lepe[((size_t)(bt * H_ + h) * W_ + (strip * 4 + wi)) * C_ + c] = (bf16)acc;
        }
    }
}

// ---------------------------------------------------------------------------
// Kernel 3: windowed attention. Fixed softmax max (exp2 domain), lane-local
// softmax+PV (no cross-lane traffic after staging). 320 virtual zero-logit
// tokens folded into the denominator. LePE added in epilogue.
// grid = NW*NH = 224 blocks, 256 threads (4 waves x 112 q-rows)
// ---------------------------------------------------------------------------
__launch_bounds__(256, 1)
__global__ void attn_kernel(const float* __restrict__ q_in, const float* __restrict__ k_in,
                            const float* __restrict__ v_in, const float* __restrict__ pm_k,
                            const float* __restrict__ pm_v, const bf16* __restrict__ lepe,
                            float* __restrict__ out) {
    // K row-major [tok][hd], row stride 40 ushorts (80B)
    __shared__ __align__(16) u16 Ks[SEQ_ * 40];
    // V transposed [hd][tok], row stride 584 ushorts (1168B)
    __shared__ __align__(16) u16 Vt[32 * 584];

    const int tid  = threadIdx.x;
    const int nh   = blockIdx.x & 7;
    const int nwi  = blockIdx.x >> 3;
    const int b    = nwi / NWW_;
    const int ww   = nwi % NWW_;
    const int cbase = nh * 32;

    // ---- stage K (row-major, padded) and V (transposed) into LDS ----
    for (int idx = tid; idx < SEQ_ * 4; idx += 256) {
        const int tok = idx >> 2, slot = idx & 3;
        uint4v dk = {0, 0, 0, 0}, dv = {0, 0, 0, 0};
        if (tok < TQ_) {
            const int t = tok / 224, r = tok % 224;
            const int h = r >> 2, wi = r & 3;
            const size_t off =
                ((size_t)(((b * T_ + t) * H_ + h) * W_ + (ww * 4 + wi))) * C_ + cbase + slot * 8;
            const f32x4 k0 = *(const f32x4*)(k_in + off);
            const f32x4 k1 = *(const f32x4*)(k_in + off + 4);
            const f32x4 v0 = *(const f32x4*)(v_in + off);
            const f32x4 v1 = *(const f32x4*)(v_in + off + 4);
            dk = uint4v{pack2(k0[0], k0[1]), pack2(k0[2], k0[3]),
                        pack2(k1[0], k1[1]), pack2(k1[2], k1[3])};
            dv = uint4v{pack2(v0[0], v0[1]), pack2(v0[2], v0[3]),
                        pack2(v1[0], v1[1]), pack2(v1[2], v1[3])};
        } else if (tok < REAL_) {
            const int i = tok - TQ_;
            const int t = i / 56, r = i % 56;
            const int kh = r / 14, jj = r % 14;
            const size_t off =
                ((size_t)(((b * T_ + t) * 4 + kh) * NWW_ + jj)) * C_ + cbase + slot * 8;
            const float* pk = pm_k + off;
            const float* pv = pm_v + off;
            dk = uint4v{pack2(pk[0], pk[1]), pack2(pk[2], pk[3]),
                        pack2(pk[4], pk[5]), pack2(pk[6], pk[7])};
            dv = uint4v{pack2(pv[0], pv[1]), pack2(pv[2], pv[3]),
                        pack2(pv[4], pv[5]), pack2(pv[6], pv[7])};
        }
        *(uint4v*)(Ks + tok * 40 + slot * 8) = dk;
        u16 es[8];
        #pragma unroll
        for (int e = 0; e < 8; ++e) es[e] = (u16)((dv[e >> 1] >> ((e & 1) * 16)) & 0xffff);
        #pragma unroll
        for (int e = 0; e < 8; ++e) Vt[(slot * 8 + e) * 584 + tok] = es[e];
    }
    __syncthreads();

    const int lane = tid & 63;
    const int wv   = tid >> 6;
    const int l15  = lane & 15;
    const int g    = lane >> 4;
    const float QS = 0.17677669529663687f * 1.4426950408889634f; // HD^-0.5 * log2(e)

    // ---- Q fragments (7 tiles of 16 rows per wave), scaled into exp2 domain ----
    bf16x8 qf[7];
    #pragma unroll
    for (int qt = 0; qt < 7; ++qt) {
        const int qrow = wv * 112 + qt * 16 + l15;
        const int t = qrow / 224, r = qrow % 224;
        const int h = r >> 2, wi = r & 3;
        const size_t off =
            ((size_t)(((b * T_ + t) * H_ + h) * W_ + (ww * 4 + wi))) * C_ + cbase + g * 8;
        const f32x4 a0 = *(const f32x4*)(q_in + off);
        const f32x4 a1 = *(const f32x4*)(q_in + off + 4);
        const uint4v qp = {pack2(a0[0] * QS, a0[1] * QS), pack2(a0[2] * QS, a0[3] * QS),
                           pack2(a1[0] * QS, a1[1] * QS), pack2(a1[2] * QS, a1[3] * QS)};
        qf[qt] = __builtin_bit_cast(bf16x8, qp);
    }

    f32x4 o[7][2];
    float ssum[7];
    const f32x4 zf = {0.f, 0.f, 0.f, 0.f};
    #pragma unroll
    for (int qt = 0; qt < 7; ++qt) {
        o[qt][0] = zf; o[qt][1] = zf; ssum[qt] = 0.f;
    }

    // ---- loop over 18 chunks of 32 tokens ----
    for (int kc = 0; kc < SEQ_ / 32; ++kc) {
        const int kt0 = kc * 32;
        const bf16x8 ka = *(const bf16x8*)(Ks + (kt0 + l15) * 40 + g * 8);
        const bf16x8 kb = *(const bf16x8*)(Ks + (kt0 + 16 + l15) * 40 + g * 8);
#if USE_MFMA16
        // V^T A-fragments for 16x16x16 PV: lane(l15,g) row=l15(+16*h2), k=g*4+e
        const s16x4 va00 = __builtin_bit_cast(s16x4, *(const uint2v*)(Vt + l15 * 584 + kt0 + g * 4));
        const s16x4 va01 = __builtin_bit_cast(s16x4, *(const uint2v*)(Vt + l15 * 584 + kt0 + 16 + g * 4));
        const s16x4 va10 = __builtin_bit_cast(s16x4, *(const uint2v*)(Vt + (16 + l15) * 584 + kt0 + g * 4));
        const s16x4 va11 = __builtin_bit_cast(s16x4, *(const uint2v*)(Vt + (16 + l15) * 584 + kt0 + 16 + g * 4));
#else
        const bf16x8 va = *(const bf16x8*)(Vt + l15 * 584 + kt0 + g * 8);
        const bf16x8 vb = *(const bf16x8*)(Vt + (16 + l15) * 584 + kt0 + g * 8);
#endif

        #pragma unroll
        for (int qt = 0; qt < 7; ++qt) {
            // S^T tiles: lane holds scores for q = l15, ktok = kt0 + (tile*16 + g*4 + r)
            const f32x4 s0 = __builtin_amdgcn_mfma_f32_16x16x32_bf16(ka, qf[qt], zf, 0, 0, 0);
            const f32x4 s1 = __builtin_amdgcn_mfma_f32_16x16x32_bf16(kb, qf[qt], zf, 0, 0, 0);

            const float p0 = __builtin_amdgcn_exp2f(s0[0] - MEXP_);
            const float p1 = __builtin_amdgcn_exp2f(s0[1] - MEXP_);
            const float p2 = __builtin_amdgcn_exp2f(s0[2] - MEXP_);
            const float p3 = __builtin_amdgcn_exp2f(s0[3] - MEXP_);
            const float p4 = __builtin_amdgcn_exp2f(s1[0] - MEXP_);
            const float p5 = __builtin_amdgcn_exp2f(s1[1] - MEXP_);
            const float p6 = __builtin_amdgcn_exp2f(s1[2] - MEXP_);
            const float p7 = __builtin_amdgcn_exp2f(s1[3] - MEXP_);

            ssum[qt] += ((p0 + p1) + (p2 + p3)) + ((p4 + p5) + (p6 + p7));

            const uint w0 = pack2(p0, p1), w1 = pack2(p2, p3);
            const uint w2 = pack2(p4, p5), w3 = pack2(p6, p7);
#if USE_MFMA16
            // B-operand of 16x16x16 == S^T layout: col=l15=q, k=g*4+r. Lane-local.
            const s16x4 pb0 = __builtin_bit_cast(s16x4, uint2v{w0, w1});
            const s16x4 pb1 = __builtin_bit_cast(s16x4, uint2v{w2, w3});
            o[qt][0] = __builtin_amdgcn_mfma_f32_16x16x16bf16_1k(va00, pb0, o[qt][0], 0, 0, 0);
            o[qt][0] = __builtin_amdgcn_mfma_f32_16x16x16bf16_1k(va01, pb1, o[qt][0], 0, 0, 0);
            o[qt][1] = __builtin_amdgcn_mfma_f32_16x16x16bf16_1k(va10, pb0, o[qt][1], 0, 0, 0);
            o[qt][1] = __builtin_amdgcn_mfma_f32_16x16x16bf16_1k(va11, pb1, o[qt][1], 0, 0, 0);
#else
            // rearrange P to 16x16x32 A-fragment in-register (race-free shuffles)
            const int baseln = l15 + ((g & 1) << 5);
            const uint sA = (g & 2) ? w2 : w0;
            const uint sB = (g & 2) ? w3 : w1;
            const uint o0 = (uint)__shfl((int)sA, baseln);
            const uint o1 = (uint)__shfl((int)sB, baseln);
            const uint o2 = (uint)__shfl((int)sA, baseln + 16);
            const uint o3 = (uint)__shfl((int)sB, baseln + 16);
            const bf16x8 pf = __builtin_bit_cast(bf16x8, uint4v{o0, o1, o2, o3});
            o[qt][0] = __builtin_amdgcn_mfma_f32_16x16x32_bf16(pf, va, o[qt][0], 0, 0, 0);
            o[qt][1] = __builtin_amdgcn_mfma_f32_16x16x32_bf16(pf, vb, o[qt][1], 0, 0, 0);
#endif
        }
    }

    // ---- epilogue: reduce denominator across g, add virtual zeros, LePE, store ----
    #pragma unroll
    for (int qt = 0; qt < 7; ++qt) {
        float den = ssum[qt];
        den += __shfl_xor(den, 16);
        den += __shfl_xor(den, 32);
        den += VIRT_ * 0.0000152587890625f; // 320 * 2^-16
        const float osc = 1.0f / den;       // valid in every lane, for q = l15

#if USE_MFMA16
        // o[qt][h2] reg r = O[q=l15][cbase + h2*16 + g*4 + r] — fully lane-local
        const int qrow = wv * 112 + qt * 16 + l15;
        const int t = qrow / 224, rr = qrow % 224;
        const int h = rr >> 2, wi = rr & 3;
        const size_t off =
            ((size_t)(((b * T_ + t) * H_ + h) * W_ + (ww * 4 + wi))) * C_ + cbase;
        #pragma unroll
        for (int h2 = 0; h2 < 2; ++h2) {
            const int co = h2 * 16 + g * 4;
            const bf16x4 lp = *(const bf16x4*)(lepe + off + co);
            f32x4 val;
            #pragma unroll
            for (int r = 0; r < 4; ++r) val[r] = o[qt][h2][r] * osc + (float)lp[r];
            *(f32x4*)(out + off + co) = val;
        }
#else
        // o[qt][j] reg r = O[q = g*4+r][hd = l15 + 16*j]
        #pragma unroll
        for (int r = 0; r < 4; ++r) {
            const float oscr = __shfl(osc, g * 4 + r);
            const int qrow = wv * 112 + qt * 16 + g * 4 + r;
            const int t = qrow / 224, rr = qrow % 224;
            const int h = rr >> 2, wi = rr & 3;
            const size_t off =
                ((size_t)(((b * T_ + t) * H_ + h) * W_ + (ww * 4 + wi))) * C_ + cbase + l15;
            out[off]      = o[qt][0][r] * oscr + (float)lepe[off];
            out[off + 16] = o[qt][1][r] * oscr + (float)lepe[off + 16];
        }
#endif
    }
}

// ---------------------------------------------------------------------------
extern "C" void kernel_launch(void* const* d_in, const int* in_sizes, int n_in,
                              void* d_out, int out_size, void* d_ws, size_t ws_size,
                              hipStream_t stream) {
    const float* qkv = (const float*)d_in[0];
    const float* gw  = (const float*)d_in[1];
    const float* gb  = (const float*)d_in[2];
    const float* pw  = (const float*)d_in[3];
    const float* pb  = (const float*)d_in[4];

    const size_t plane = (size_t)B_ * T_ * H_ * W_ * C_; // 3,211,264
    const float* q_in = qkv;
    const float* k_in = qkv + plane;
    const float* v_in = qkv + 2 * plane;

    const size_t pm_elems = (size_t)B_ * T_ * 4 * NWW_ * C_; // 57,344
    float* pm_k = (float*)d_ws;
    float* pm_v = pm_k + pm_elems;
    bf16*  lepe = (bf16*)(pm_v + pm_elems);
    float* outp = (float*)d_out;

    hipMemsetAsync(d_ws, 0, 2 * pm_elems * sizeof(float), stream);
    hipLaunchKernelGGL(pool_kernel, dim3(B_ * T_ * NWW_ * 4), dim3(256), 0, stream,
                       k_in, v_in, pw, pb, pm_k, pm_v);
    hipLaunchKernelGGL(lepe_kernel, dim3(B_ * T_ * H_), dim3(256), 0, stream,
                       v_in, gw, gb, lepe);
    hipLaunchKernelGGL(attn_kernel, dim3(28 * 8), dim3(256), 0, stream,
                       q_in, k_in, v_in, pm_k, pm_v, lepe, outp);
}

// Round 5
// 47.267 us; speedup vs baseline: 1.2379x; 1.2280x over previous
//
#include <hip/hip_runtime.h>
#include <hip/hip_bf16.h>

// Problem constants
#define B_   2
#define T_   2
#define H_   56
#define W_   56
#define C_   256
#define NH_  8
#define HD_  32
#define NWW_ 14      // windows along W (W_sp=4)
#define TQ_  448     // queries per window = T*56*4
#define SEQ_ 576     // staged K/V tokens: 448 window + 112 pooled + 16 zero pad
#define REAL_ 560
#define VIRT_ 320.0f // remaining zero-logit pooled tokens folded analytically
#define MEXP_ 16.0f  // fixed softmax max (exp2 domain); realized |logit*log2e| < ~10
#define PMSTR_ 57344 // one pool-partial tensor: B*T*4*NWW*C

typedef __bf16 bf16;
typedef __bf16 bf16x8 __attribute__((ext_vector_type(8)));
typedef __bf16 bf16x4 __attribute__((ext_vector_type(4)));
typedef float  f32x4  __attribute__((ext_vector_type(4)));
typedef short  s16x4  __attribute__((ext_vector_type(4)));
typedef unsigned int  uint;
typedef uint   uint4v __attribute__((ext_vector_type(4)));
typedef uint   uint2v __attribute__((ext_vector_type(2)));
typedef unsigned short u16;

#if defined(__has_builtin)
#  if __has_builtin(__builtin_amdgcn_mfma_f32_16x16x16bf16_1k)
#    define USE_MFMA16 1
#  endif
#endif
#ifndef USE_MFMA16
#  define USE_MFMA16 0
#endif

__device__ __forceinline__ uint pack2(float a, float b) {
    u16 ha = __builtin_bit_cast(u16, (bf16)a);
    u16 hb = __builtin_bit_cast(u16, (bf16)b);
    return (uint)ha | ((uint)hb << 16);
}

// ---------------------------------------------------------------------------
// Fused pre-kernel.
// Blocks 0..223: pool quarter-partials (b,t,j,quarter), 256 threads (c).
//   Writes pm{k,v}_part[quarter][b,t,s,j,c] — no atomics, no memset.
// Blocks 224..1791: LePE depthwise 3x3 within 56x4 strips, (bt,h,strip-pair).
// ---------------------------------------------------------------------------
__global__ void pre_kernel(const float* __restrict__ k_in, const float* __restrict__ v_in,
                           const float* __restrict__ pool_w, const float* __restrict__ pool_b,
                           const float* __restrict__ gw, const float* __restrict__ gb,
                           float* __restrict__ pmk_part, float* __restrict__ pmv_part,
                           bf16* __restrict__ lepe) {
    __shared__ float pws[4][56];
    const int bid = blockIdx.x;
    const int c   = threadIdx.x;

    if (bid < 224) {
        // ---- pool quarter-partial ----
        const int quarter = bid & 3;
        const int bj = bid >> 2;
        const int j  = bj % NWW_;
        const int t  = (bj / NWW_) % T_;
        const int b  = bj / (NWW_ * T_);
        const int n0 = quarter * 56;

        if (c < 224) pws[c / 56][c % 56] = pool_w[(c / 56) * 224 + n0 + (c % 56)];
        __syncthreads();

        float ak[4], av[4];
        #pragma unroll
        for (int s = 0; s < 4; ++s) {
            ak[s] = (quarter == 0) ? pool_b[s] : 0.f;
            av[s] = 0.f;
        }
        for (int i = 0; i < 56; ++i) {
            const int n = n0 + i;
            const int h = n >> 2, wi = n & 3;
            const size_t off = ((size_t)(((b * T_ + t) * H_ + h) * W_ + (j * 4 + wi))) * C_ + c;
            const float kv = k_in[off];
            const float vv = v_in[off];
            #pragma unroll
            for (int s = 0; s < 4; ++s) {
                ak[s] += kv * pws[s][i];
                av[s] += vv * pws[s][i];
            }
        }
        #pragma unroll
        for (int s = 0; s < 4; ++s) {
            const size_t o = (size_t)quarter * PMSTR_ +
                             ((size_t)(((b * T_ + t) * 4 + s) * NWW_ + j)) * C_ + c;
            pmk_part[o] = ak[s];
            pmv_part[o] = av[s];
        }
    } else {
        // ---- LePE: (bt, h, strip-pair), 2 strips per block ----
        const int r  = bid - 224;
        const int sp = r % 7;
        const int h  = (r / 7) % H_;
        const int bt = r / (7 * H_);

        float wv9[9];
        #pragma unroll
        for (int k = 0; k < 9; ++k) wv9[k] = gw[c * 9 + k];
        const float bias = gb[c];

        #pragma unroll
        for (int s2 = 0; s2 < 2; ++s2) {
            const int strip = sp * 2 + s2;
            float tile[3][4];
            #pragma unroll
            for (int dy = 0; dy < 3; ++dy) {
                const int hh = h - 1 + dy;
                const bool ok = (hh >= 0 && hh < H_);
                #pragma unroll
                for (int x = 0; x < 4; ++x) {
                    tile[dy][x] = ok
                        ? v_in[((size_t)(bt * H_ + hh) * W_ + (strip * 4 + x)) * C_ + c]
                        : 0.f;
                }
            }
            #pragma unroll
            for (int wi = 0; wi < 4; ++wi) {
                float acc = bias;
                #pragma unroll
                for (int dy = 0; dy < 3; ++dy) {
                    #pragma unroll
                    for (int dx = -1; dx <= 1; ++dx) {
                        const int xx = wi + dx;
                        if (xx >= 0 && xx < 4)
                            acc += wv9[dy * 3 + dx + 1] * tile[dy][xx];
                    }
                }
                lepe[((size_t)(bt * H_ + h) * W_ + (strip * 4 + wi)) * C_ + c] = (bf16)acc;
            }
        }
    }
}

// ---------------------------------------------------------------------------
// Attention: 12 waves (768 thr). wave wv: q-group = wv&3 (112 rows),
// K-segment = wv>>2 (6 of 18 chunks). Fixed-max softmax -> linear partial
// combine through LDS (staging region reused post-barrier). LePE in epilogue.
// grid = NW*NH = 224 blocks
// ---------------------------------------------------------------------------
__launch_bounds__(768, 1)
__global__ void attn_kernel(const float* __restrict__ q_in, const float* __restrict__ k_in,
                            const float* __restrict__ v_in, const float* __restrict__ pm_k,
                            const float* __restrict__ pm_v, const bf16* __restrict__ lepe,
                            float* __restrict__ out) {
    // union region: staging {Ks 576x40 u16 | Vt 32x584 u16} then combine
    // {opart 2 segs x 448 q x 36-stride f32 | ssp 2x448 f32}
    __shared__ __align__(16) u16 smem[66304];
    u16* Ks = smem;            // 23040 u16
    u16* Vt = smem + 23040;    // 18688 u16

    const int tid  = threadIdx.x;
    const int nh   = blockIdx.x & 7;
    const int nwi  = blockIdx.x >> 3;
    const int b    = nwi / NWW_;
    const int ww   = nwi % NWW_;
    const int cbase = nh * 32;

    // ---- stage K (row-major, padded) and V (transposed) into LDS ----
    for (int idx = tid; idx < SEQ_ * 4; idx += 768) {
        const int tok = idx >> 2, slot = idx & 3;
        uint4v dk = {0, 0, 0, 0}, dv = {0, 0, 0, 0};
        if (tok < TQ_) {
            const int t = tok / 224, r = tok % 224;
            const int h = r >> 2, wi = r & 3;
            const size_t off =
                ((size_t)(((b * T_ + t) * H_ + h) * W_ + (ww * 4 + wi))) * C_ + cbase + slot * 8;
            const f32x4 k0 = *(const f32x4*)(k_in + off);
            const f32x4 k1 = *(const f32x4*)(k_in + off + 4);
            const f32x4 v0 = *(const f32x4*)(v_in + off);
            const f32x4 v1 = *(const f32x4*)(v_in + off + 4);
            dk = uint4v{pack2(k0[0], k0[1]), pack2(k0[2], k0[3]),
                        pack2(k1[0], k1[1]), pack2(k1[2], k1[3])};
            dv = uint4v{pack2(v0[0], v0[1]), pack2(v0[2], v0[3]),
                        pack2(v1[0], v1[1]), pack2(v1[2], v1[3])};
        } else if (tok < REAL_) {
            const int i = tok - TQ_;
            const int t = i / 56, r = i % 56;
            const int kh = r / 14, jj = r % 14;
            const size_t off =
                ((size_t)(((b * T_ + t) * 4 + kh) * NWW_ + jj)) * C_ + cbase + slot * 8;
            f32x4 k0 = {0,0,0,0}, k1 = {0,0,0,0}, v0 = {0,0,0,0}, v1 = {0,0,0,0};
            #pragma unroll
            for (int pq = 0; pq < 4; ++pq) {
                const float* pk = pm_k + (size_t)pq * PMSTR_ + off;
                const float* pv = pm_v + (size_t)pq * PMSTR_ + off;
                k0 += *(const f32x4*)pk;  k1 += *(const f32x4*)(pk + 4);
                v0 += *(const f32x4*)pv;  v1 += *(const f32x4*)(pv + 4);
            }
            dk = uint4v{pack2(k0[0], k0[1]), pack2(k0[2], k0[3]),
                        pack2(k1[0], k1[1]), pack2(k1[2], k1[3])};
            dv = uint4v{pack2(v0[0], v0[1]), pack2(v0[2], v0[3]),
                        pack2(v1[0], v1[1]), pack2(v1[2], v1[3])};
        }
        *(uint4v*)(Ks + tok * 40 + slot * 8) = dk;
        u16 es[8];
        #pragma unroll
        for (int e = 0; e < 8; ++e) es[e] = (u16)((dv[e >> 1] >> ((e & 1) * 16)) & 0xffff);
        #pragma unroll
        for (int e = 0; e < 8; ++e) Vt[(slot * 8 + e) * 584 + tok] = es[e];
    }
    __syncthreads();

    const int lane = tid & 63;
    const int wv   = tid >> 6;     // 0..11
    const int qg   = wv & 3;       // q-group (112 rows)
    const int seg  = wv >> 2;      // K-segment (0..2)
    const int l15  = lane & 15;
    const int g    = lane >> 4;
    const float QS = 0.17677669529663687f * 1.4426950408889634f; // HD^-0.5 * log2(e)

    // ---- Q fragments (7 tiles of 16 rows per q-group), exp2 domain ----
    bf16x8 qf[7];
    #pragma unroll
    for (int qt = 0; qt < 7; ++qt) {
        const int qrow = qg * 112 + qt * 16 + l15;
        const int t = qrow / 224, r = qrow % 224;
        const int h = r >> 2, wi = r & 3;
        const size_t off =
            ((size_t)(((b * T_ + t) * H_ + h) * W_ + (ww * 4 + wi))) * C_ + cbase + g * 8;
        const f32x4 a0 = *(const f32x4*)(q_in + off);
        const f32x4 a1 = *(const f32x4*)(q_in + off + 4);
        const uint4v qp = {pack2(a0[0] * QS, a0[1] * QS), pack2(a0[2] * QS, a0[3] * QS),
                           pack2(a1[0] * QS, a1[1] * QS), pack2(a1[2] * QS, a1[3] * QS)};
        qf[qt] = __builtin_bit_cast(bf16x8, qp);
    }

    f32x4 o[7][2];
    float ssum[7];
    const f32x4 zf = {0.f, 0.f, 0.f, 0.f};
    #pragma unroll
    for (int qt = 0; qt < 7; ++qt) {
        o[qt][0] = zf; o[qt][1] = zf; ssum[qt] = 0.f;
    }

    // ---- this segment's 6 chunks of 32 tokens ----
    const int kc0 = seg * 6;
    for (int kc = kc0; kc < kc0 + 6; ++kc) {
        const int kt0 = kc * 32;
        const bf16x8 ka = *(const bf16x8*)(Ks + (kt0 + l15) * 40 + g * 8);
        const bf16x8 kb = *(const bf16x8*)(Ks + (kt0 + 16 + l15) * 40 + g * 8);
#if USE_MFMA16
        const s16x4 va00 = __builtin_bit_cast(s16x4, *(const uint2v*)(Vt + l15 * 584 + kt0 + g * 4));
        const s16x4 va01 = __builtin_bit_cast(s16x4, *(const uint2v*)(Vt + l15 * 584 + kt0 + 16 + g * 4));
        const s16x4 va10 = __builtin_bit_cast(s16x4, *(const uint2v*)(Vt + (16 + l15) * 584 + kt0 + g * 4));
        const s16x4 va11 = __builtin_bit_cast(s16x4, *(const uint2v*)(Vt + (16 + l15) * 584 + kt0 + 16 + g * 4));
#else
        const bf16x8 va = *(const bf16x8*)(Vt + l15 * 584 + kt0 + g * 8);
        const bf16x8 vb = *(const bf16x8*)(Vt + (16 + l15) * 584 + kt0 + g * 8);
#endif

        #pragma unroll
        for (int qt = 0; qt < 7; ++qt) {
            const f32x4 s0 = __builtin_amdgcn_mfma_f32_16x16x32_bf16(ka, qf[qt], zf, 0, 0, 0);
            const f32x4 s1 = __builtin_amdgcn_mfma_f32_16x16x32_bf16(kb, qf[qt], zf, 0, 0, 0);

            const float p0 = __builtin_amdgcn_exp2f(s0[0] - MEXP_);
            const float p1 = __builtin_amdgcn_exp2f(s0[1] - MEXP_);
            const float p2 = __builtin_amdgcn_exp2f(s0[2] - MEXP_);
            const float p3 = __builtin_amdgcn_exp2f(s0[3] - MEXP_);
            const float p4 = __builtin_amdgcn_exp2f(s1[0] - MEXP_);
            const float p5 = __builtin_amdgcn_exp2f(s1[1] - MEXP_);
            const float p6 = __builtin_amdgcn_exp2f(s1[2] - MEXP_);
            const float p7 = __builtin_amdgcn_exp2f(s1[3] - MEXP_);

            ssum[qt] += ((p0 + p1) + (p2 + p3)) + ((p4 + p5) + (p6 + p7));

            const uint w0 = pack2(p0, p1), w1 = pack2(p2, p3);
            const uint w2 = pack2(p4, p5), w3 = pack2(p6, p7);
#if USE_MFMA16
            const s16x4 pb0 = __builtin_bit_cast(s16x4, uint2v{w0, w1});
            const s16x4 pb1 = __builtin_bit_cast(s16x4, uint2v{w2, w3});
            o[qt][0] = __builtin_amdgcn_mfma_f32_16x16x16bf16_1k(va00, pb0, o[qt][0], 0, 0, 0);
            o[qt][0] = __builtin_amdgcn_mfma_f32_16x16x16bf16_1k(va01, pb1, o[qt][0], 0, 0, 0);
            o[qt][1] = __builtin_amdgcn_mfma_f32_16x16x16bf16_1k(va10, pb0, o[qt][1], 0, 0, 0);
            o[qt][1] = __builtin_amdgcn_mfma_f32_16x16x16bf16_1k(va11, pb1, o[qt][1], 0, 0, 0);
#else
            const int baseln = l15 + ((g & 1) << 5);
            const uint sA = (g & 2) ? w2 : w0;
            const uint sB = (g & 2) ? w3 : w1;
            const uint o0 = (uint)__shfl((int)sA, baseln);
            const uint o1 = (uint)__shfl((int)sB, baseln);
            const uint o2 = (uint)__shfl((int)sA, baseln + 16);
            const uint o3 = (uint)__shfl((int)sB, baseln + 16);
            const bf16x8 pf = __builtin_bit_cast(bf16x8, uint4v{o0, o1, o2, o3});
            o[qt][0] = __builtin_amdgcn_mfma_f32_16x16x32_bf16(pf, va, o[qt][0], 0, 0, 0);
            o[qt][1] = __builtin_amdgcn_mfma_f32_16x16x32_bf16(pf, vb, o[qt][1], 0, 0, 0);
#endif
        }
    }

    // ---- reduce denominator across g within each wave (q = l15) ----
    float sred[7];
    #pragma unroll
    for (int qt = 0; qt < 7; ++qt) {
        float s = ssum[qt];
        s += __shfl_xor(s, 16);
        s += __shfl_xor(s, 32);
        sred[qt] = s;
    }

    __syncthreads();  // all LDS reads of Ks/Vt done; region becomes opart/ssp

    float* opart = (float*)smem;       // 2 x 448 x 36-stride
    float* ssp   = opart + 2 * 16128;  // 2 x 448

    if (seg > 0) {
        const int so = (seg - 1) * 16128;
#if USE_MFMA16
        #pragma unroll
        for (int qt = 0; qt < 7; ++qt) {
            const int q = qg * 112 + qt * 16 + l15;
            *(f32x4*)(opart + so + q * 36 + g * 4)      = o[qt][0];
            *(f32x4*)(opart + so + q * 36 + 16 + g * 4) = o[qt][1];
        }
        if (g == 0) {
            #pragma unroll
            for (int qt = 0; qt < 7; ++qt)
                ssp[(seg - 1) * 448 + qg * 112 + qt * 16 + l15] = sred[qt];
        }
#else
        #pragma unroll
        for (int qt = 0; qt < 7; ++qt) {
            #pragma unroll
            for (int r = 0; r < 4; ++r) {
                const int q = qg * 112 + qt * 16 + g * 4 + r;
                opart[so + q * 36 + l15]      = o[qt][0][r];
                opart[so + q * 36 + l15 + 16] = o[qt][1][r];
            }
        }
        if (g == 0) {
            #pragma unroll
            for (int qt = 0; qt < 7; ++qt)
                ssp[(seg - 1) * 448 + qg * 112 + qt * 16 + l15] = sred[qt];
        }
#endif
    }
    __syncthreads();

    if (seg == 0) {
        #pragma unroll
        for (int qt = 0; qt < 7; ++qt) {
            const int q = qg * 112 + qt * 16 + l15;
            const float den = sred[qt] + ssp[q] + ssp[448 + q]
                            + VIRT_ * 0.0000152587890625f; // 320 * 2^-16
            const float osc = 1.0f / den;                  // for q = l15

#if USE_MFMA16
            const int t = q / 224, rr = q % 224;
            const int h = rr >> 2, wi = rr & 3;
            const size_t off =
                ((size_t)(((b * T_ + t) * H_ + h) * W_ + (ww * 4 + wi))) * C_ + cbase;
            #pragma unroll
            for (int h2 = 0; h2 < 2; ++h2) {
                const int co = h2 * 16 + g * 4;
                const f32x4 pa = *(const f32x4*)(opart + q * 36 + co);
                const f32x4 pb = *(const f32x4*)(opart + 16128 + q * 36 + co);
                const bf16x4 lp = *(const bf16x4*)(lepe + off + co);
                f32x4 val;
                #pragma unroll
                for (int r = 0; r < 4; ++r)
                    val[r] = (o[qt][h2][r] + pa[r] + pb[r]) * osc + (float)lp[r];
                *(f32x4*)(out + off + co) = val;
            }
#else
            #pragma unroll
            for (int r = 0; r < 4; ++r) {
                const float oscr = __shfl(osc, g * 4 + r);
                const int qrow = qg * 112 + qt * 16 + g * 4 + r;
                const int t = qrow / 224, rr = qrow % 224;
                const int h = rr >> 2, wi = rr & 3;
                const size_t off =
                    ((size_t)(((b * T_ + t) * H_ + h) * W_ + (ww * 4 + wi))) * C_ + cbase + l15;
                out[off] = (o[qt][0][r] + opart[qrow * 36 + l15] +
                            opart[16128 + qrow * 36 + l15]) * oscr + (float)lepe[off];
                out[off + 16] = (o[qt][1][r] + opart[qrow * 36 + l15 + 16] +
                                 opart[16128 + qrow * 36 + l15 + 16]) * oscr + (float)lepe[off + 16];
            }
#endif
        }
    }
}

// ---------------------------------------------------------------------------
extern "C" void kernel_launch(void* const* d_in, const int* in_sizes, int n_in,
                              void* d_out, int out_size, void* d_ws, size_t ws_size,
                              hipStream_t stream) {
    const float* qkv = (const float*)d_in[0];
    const float* gw  = (const float*)d_in[1];
    const float* gb  = (const float*)d_in[2];
    const float* pw  = (const float*)d_in[3];
    const float* pb  = (const float*)d_in[4];

    const size_t plane = (size_t)B_ * T_ * H_ * W_ * C_; // 3,211,264
    const float* q_in = qkv;
    const float* k_in = qkv + plane;
    const float* v_in = qkv + 2 * plane;

    float* pmk_part = (float*)d_ws;                 // 4 * 57344 f32
    float* pmv_part = pmk_part + 4 * PMSTR_;        // 4 * 57344 f32
    bf16*  lepe     = (bf16*)(pmv_part + 4 * PMSTR_);
    float* outp     = (float*)d_out;

    hipLaunchKernelGGL(pre_kernel, dim3(224 + 1568), dim3(256), 0, stream,
                       k_in, v_in, pw, pb, gw, gb, pmk_part, pmv_part, lepe);
    hipLaunchKernelGGL(attn_kernel, dim3(28 * 8), dim3(768), 0, stream,
                       q_in, k_in, v_in, pmk_part, pmv_part, lepe, outp);
}

// Round 6
// 44.510 us; speedup vs baseline: 1.3146x; 1.0620x over previous
//
#include <hip/hip_runtime.h>
#include <hip/hip_bf16.h>

// Problem constants
#define B_   2
#define T_   2
#define H_   56
#define W_   56
#define C_   256
#define NH_  8
#define HD_  32
#define NWW_ 14      // windows along W (W_sp=4)
#define TQ_  448     // queries per window = T*56*4
#define SEQ_ 576     // staged K/V tokens: 448 window + 112 pooled + 16 zero pad
#define REAL_ 560
#define VIRT_ 320.0f // remaining zero-logit pooled tokens folded analytically
#define MEXP_ 16.0f  // fixed softmax max (exp2 domain); realized |logit*log2e| < ~10
#define PMSTR_ 57344 // one pool-partial tensor: B*T*4*NWW*C

typedef __bf16 bf16;
typedef __bf16 bf16x8 __attribute__((ext_vector_type(8)));
typedef __bf16 bf16x4 __attribute__((ext_vector_type(4)));
typedef float  f32x4  __attribute__((ext_vector_type(4)));
typedef short  s16x4  __attribute__((ext_vector_type(4)));
typedef unsigned int  uint;
typedef uint   uint4v __attribute__((ext_vector_type(4)));
typedef uint   uint2v __attribute__((ext_vector_type(2)));
typedef unsigned short u16;

#if defined(__has_builtin)
#  if __has_builtin(__builtin_amdgcn_mfma_f32_16x16x16bf16_1k)
#    define USE_MFMA16 1
#  endif
#endif
#ifndef USE_MFMA16
#  define USE_MFMA16 0
#endif

__device__ __forceinline__ uint pack2(float a, float b) {
    u16 ha = __builtin_bit_cast(u16, (bf16)a);
    u16 hb = __builtin_bit_cast(u16, (bf16)b);
    return (uint)ha | ((uint)hb << 16);
}

// ---------------------------------------------------------------------------
// Fused pre-kernel.
// Blocks 0..223: pool quarter-partials (b,t,j,quarter), 256 threads (c).
//   Writes pm{k,v}_part[quarter][b,t,s,j,c] — no atomics, no memset.
// Blocks 224..1791: LePE depthwise 3x3 within 56x4 strips, (bt,h,strip-pair).
// ---------------------------------------------------------------------------
__global__ void pre_kernel(const float* __restrict__ k_in, const float* __restrict__ v_in,
                           const float* __restrict__ pool_w, const float* __restrict__ pool_b,
                           const float* __restrict__ gw, const float* __restrict__ gb,
                           float* __restrict__ pmk_part, float* __restrict__ pmv_part,
                           bf16* __restrict__ lepe) {
    __shared__ float pws[4][56];
    const int bid = blockIdx.x;
    const int c   = threadIdx.x;

    if (bid < 224) {
        // ---- pool quarter-partial ----
        const int quarter = bid & 3;
        const int bj = bid >> 2;
        const int j  = bj % NWW_;
        const int t  = (bj / NWW_) % T_;
        const int b  = bj / (NWW_ * T_);
        const int n0 = quarter * 56;

        if (c < 224) pws[c / 56][c % 56] = pool_w[(c / 56) * 224 + n0 + (c % 56)];
        __syncthreads();

        float ak[4], av[4];
        #pragma unroll
        for (int s = 0; s < 4; ++s) {
            ak[s] = (quarter == 0) ? pool_b[s] : 0.f;
            av[s] = 0.f;
        }
        for (int i = 0; i < 56; ++i) {
            const int n = n0 + i;
            const int h = n >> 2, wi = n & 3;
            const size_t off = ((size_t)(((b * T_ + t) * H_ + h) * W_ + (j * 4 + wi))) * C_ + c;
            const float kv = k_in[off];
            const float vv = v_in[off];
            #pragma unroll
            for (int s = 0; s < 4; ++s) {
                ak[s] += kv * pws[s][i];
                av[s] += vv * pws[s][i];
            }
        }
        #pragma unroll
        for (int s = 0; s < 4; ++s) {
            const size_t o = (size_t)quarter * PMSTR_ +
                             ((size_t)(((b * T_ + t) * 4 + s) * NWW_ + j)) * C_ + c;
            pmk_part[o] = ak[s];
            pmv_part[o] = av[s];
        }
    } else {
        // ---- LePE: (bt, h, strip-pair), 2 strips per block ----
        const int r  = bid - 224;
        const int sp = r % 7;
        const int h  = (r / 7) % H_;
        const int bt = r / (7 * H_);

        float wv9[9];
        #pragma unroll
        for (int k = 0; k < 9; ++k) wv9[k] = gw[c * 9 + k];
        const float bias = gb[c];

        #pragma unroll
        for (int s2 = 0; s2 < 2; ++s2) {
            const int strip = sp * 2 + s2;
            float tile[3][4];
            #pragma unroll
            for (int dy = 0; dy < 3; ++dy) {
                const int hh = h - 1 + dy;
                const bool ok = (hh >= 0 && hh < H_);
                #pragma unroll
                for (int x = 0; x < 4; ++x) {
                    tile[dy][x] = ok
                        ? v_in[((size_t)(bt * H_ + hh) * W_ + (strip * 4 + x)) * C_ + c]
                        : 0.f;
                }
            }
            #pragma unroll
            for (int wi = 0; wi < 4; ++wi) {
                float acc = bias;
                #pragma unroll
                for (int dy = 0; dy < 3; ++dy) {
                    #pragma unroll
                    for (int dx = -1; dx <= 1; ++dx) {
                        const int xx = wi + dx;
                        if (xx >= 0 && xx < 4)
                            acc += wv9[dy * 3 + dx + 1] * tile[dy][xx];
                    }
                }
                lepe[((size_t)(bt * H_ + h) * W_ + (strip * 4 + wi)) * C_ + c] = (bf16)acc;
            }
        }
    }
}

// ---------------------------------------------------------------------------
// Attention: 14 waves (896 thr); each wave owns 2 q-tiles (16 rows each) and
// runs the full 18-chunk K loop. Tiny per-wave state (no spill). Fixed-max
// softmax (exp2 domain), lane-local PV, virtual zero tokens in denominator.
// Single barrier; per-wave epilogue. grid = NW*NH = 224 blocks.
// ---------------------------------------------------------------------------
__launch_bounds__(896, 4)
__global__ void attn_kernel(const float* __restrict__ q_in, const float* __restrict__ k_in,
                            const float* __restrict__ v_in, const float* __restrict__ pm_k,
                            const float* __restrict__ pm_v, const bf16* __restrict__ lepe,
                            float* __restrict__ out) {
    // K row-major [tok][hd], row stride 40 ushorts (80B, 16B-aligned rows)
    __shared__ __align__(16) u16 Ks[SEQ_ * 40];
    // V transposed [hd][tok], row stride 584 ushorts (1168B)
    __shared__ __align__(16) u16 Vt[32 * 584];

    const int tid  = threadIdx.x;
    const int nh   = blockIdx.x & 7;
    const int nwi  = blockIdx.x >> 3;
    const int b    = nwi / NWW_;
    const int ww   = nwi % NWW_;
    const int cbase = nh * 32;

    // ---- stage K (row-major, padded) and V (transposed) into LDS ----
    for (int idx = tid; idx < SEQ_ * 4; idx += 896) {
        const int tok = idx >> 2, slot = idx & 3;
        uint4v dk = {0, 0, 0, 0}, dv = {0, 0, 0, 0};
        if (tok < TQ_) {
            const int t = tok / 224, r = tok % 224;
            const int h = r >> 2, wi = r & 3;
            const size_t off =
                ((size_t)(((b * T_ + t) * H_ + h) * W_ + (ww * 4 + wi))) * C_ + cbase + slot * 8;
            const f32x4 k0 = *(const f32x4*)(k_in + off);
            const f32x4 k1 = *(const f32x4*)(k_in + off + 4);
            const f32x4 v0 = *(const f32x4*)(v_in + off);
            const f32x4 v1 = *(const f32x4*)(v_in + off + 4);
            dk = uint4v{pack2(k0[0], k0[1]), pack2(k0[2], k0[3]),
                        pack2(k1[0], k1[1]), pack2(k1[2], k1[3])};
            dv = uint4v{pack2(v0[0], v0[1]), pack2(v0[2], v0[3]),
                        pack2(v1[0], v1[1]), pack2(v1[2], v1[3])};
        } else if (tok < REAL_) {
            const int i = tok - TQ_;
            const int t = i / 56, r = i % 56;
            const int kh = r / 14, jj = r % 14;
            const size_t off =
                ((size_t)(((b * T_ + t) * 4 + kh) * NWW_ + jj)) * C_ + cbase + slot * 8;
            f32x4 k0 = {0,0,0,0}, k1 = {0,0,0,0}, v0 = {0,0,0,0}, v1 = {0,0,0,0};
            #pragma unroll
            for (int pq = 0; pq < 4; ++pq) {
                const float* pk = pm_k + (size_t)pq * PMSTR_ + off;
                const float* pv = pm_v + (size_t)pq * PMSTR_ + off;
                k0 += *(const f32x4*)pk;  k1 += *(const f32x4*)(pk + 4);
                v0 += *(const f32x4*)pv;  v1 += *(const f32x4*)(pv + 4);
            }
            dk = uint4v{pack2(k0[0], k0[1]), pack2(k0[2], k0[3]),
                        pack2(k1[0], k1[1]), pack2(k1[2], k1[3])};
            dv = uint4v{pack2(v0[0], v0[1]), pack2(v0[2], v0[3]),
                        pack2(v1[0], v1[1]), pack2(v1[2], v1[3])};
        }
        *(uint4v*)(Ks + tok * 40 + slot * 8) = dk;
        u16 es[8];
        #pragma unroll
        for (int e = 0; e < 8; ++e) es[e] = (u16)((dv[e >> 1] >> ((e & 1) * 16)) & 0xffff);
        #pragma unroll
        for (int e = 0; e < 8; ++e) Vt[(slot * 8 + e) * 584 + tok] = es[e];
    }
    __syncthreads();

    const int lane = tid & 63;
    const int wv   = tid >> 6;     // 0..13
    const int l15  = lane & 15;
    const int g    = lane >> 4;
    const float QS = 0.17677669529663687f * 1.4426950408889634f; // HD^-0.5 * log2(e)

    // ---- 2 q-tiles per wave: tiles wv and wv+14 (q-row = tile*16 + l15) ----
    bf16x8 qf[2];
    #pragma unroll
    for (int ti = 0; ti < 2; ++ti) {
        const int qrow = (wv + ti * 14) * 16 + l15;
        const int t = qrow / 224, r = qrow % 224;
        const int h = r >> 2, wi = r & 3;
        const size_t off =
            ((size_t)(((b * T_ + t) * H_ + h) * W_ + (ww * 4 + wi))) * C_ + cbase + g * 8;
        const f32x4 a0 = *(const f32x4*)(q_in + off);
        const f32x4 a1 = *(const f32x4*)(q_in + off + 4);
        const uint4v qp = {pack2(a0[0] * QS, a0[1] * QS), pack2(a0[2] * QS, a0[3] * QS),
                           pack2(a1[0] * QS, a1[1] * QS), pack2(a1[2] * QS, a1[3] * QS)};
        qf[ti] = __builtin_bit_cast(bf16x8, qp);
    }

    f32x4 o[2][2];
    float ssum[2];
    const f32x4 zf = {0.f, 0.f, 0.f, 0.f};
    #pragma unroll
    for (int ti = 0; ti < 2; ++ti) {
        o[ti][0] = zf; o[ti][1] = zf; ssum[ti] = 0.f;
    }

    // ---- full K loop: 18 chunks of 32 tokens ----
    for (int kc = 0; kc < SEQ_ / 32; ++kc) {
        const int kt0 = kc * 32;
        const bf16x8 ka = *(const bf16x8*)(Ks + (kt0 + l15) * 40 + g * 8);
        const bf16x8 kb = *(const bf16x8*)(Ks + (kt0 + 16 + l15) * 40 + g * 8);
#if USE_MFMA16
        const s16x4 va00 = __builtin_bit_cast(s16x4, *(const uint2v*)(Vt + l15 * 584 + kt0 + g * 4));
        const s16x4 va01 = __builtin_bit_cast(s16x4, *(const uint2v*)(Vt + l15 * 584 + kt0 + 16 + g * 4));
        const s16x4 va10 = __builtin_bit_cast(s16x4, *(const uint2v*)(Vt + (16 + l15) * 584 + kt0 + g * 4));
        const s16x4 va11 = __builtin_bit_cast(s16x4, *(const uint2v*)(Vt + (16 + l15) * 584 + kt0 + 16 + g * 4));
#else
        const bf16x8 va = *(const bf16x8*)(Vt + l15 * 584 + kt0 + g * 8);
        const bf16x8 vb = *(const bf16x8*)(Vt + (16 + l15) * 584 + kt0 + g * 8);
#endif

        #pragma unroll
        for (int ti = 0; ti < 2; ++ti) {
            // S^T tiles: lane holds scores for q = l15, ktok = kt0 + (tile*16 + g*4 + r)
            const f32x4 s0 = __builtin_amdgcn_mfma_f32_16x16x32_bf16(ka, qf[ti], zf, 0, 0, 0);
            const f32x4 s1 = __builtin_amdgcn_mfma_f32_16x16x32_bf16(kb, qf[ti], zf, 0, 0, 0);

            const float p0 = __builtin_amdgcn_exp2f(s0[0] - MEXP_);
            const float p1 = __builtin_amdgcn_exp2f(s0[1] - MEXP_);
            const float p2 = __builtin_amdgcn_exp2f(s0[2] - MEXP_);
            const float p3 = __builtin_amdgcn_exp2f(s0[3] - MEXP_);
            const float p4 = __builtin_amdgcn_exp2f(s1[0] - MEXP_);
            const float p5 = __builtin_amdgcn_exp2f(s1[1] - MEXP_);
            const float p6 = __builtin_amdgcn_exp2f(s1[2] - MEXP_);
            const float p7 = __builtin_amdgcn_exp2f(s1[3] - MEXP_);

            ssum[ti] += ((p0 + p1) + (p2 + p3)) + ((p4 + p5) + (p6 + p7));

            const uint w0 = pack2(p0, p1), w1 = pack2(p2, p3);
            const uint w2 = pack2(p4, p5), w3 = pack2(p6, p7);
#if USE_MFMA16
            // B-operand of 16x16x16 == S^T layout: col=l15=q, k=g*4+r. Lane-local.
            const s16x4 pb0 = __builtin_bit_cast(s16x4, uint2v{w0, w1});
            const s16x4 pb1 = __builtin_bit_cast(s16x4, uint2v{w2, w3});
            o[ti][0] = __builtin_amdgcn_mfma_f32_16x16x16bf16_1k(va00, pb0, o[ti][0], 0, 0, 0);
            o[ti][0] = __builtin_amdgcn_mfma_f32_16x16x16bf16_1k(va01, pb1, o[ti][0], 0, 0, 0);
            o[ti][1] = __builtin_amdgcn_mfma_f32_16x16x16bf16_1k(va10, pb0, o[ti][1], 0, 0, 0);
            o[ti][1] = __builtin_amdgcn_mfma_f32_16x16x16bf16_1k(va11, pb1, o[ti][1], 0, 0, 0);
#else
            // rearrange P to 16x16x32 A-fragment in-register (race-free shuffles)
            const int baseln = l15 + ((g & 1) << 5);
            const uint sA = (g & 2) ? w2 : w0;
            const uint sB = (g & 2) ? w3 : w1;
            const uint o0 = (uint)__shfl((int)sA, baseln);
            const uint o1 = (uint)__shfl((int)sB, baseln);
            const uint o2 = (uint)__shfl((int)sA, baseln + 16);
            const uint o3 = (uint)__shfl((int)sB, baseln + 16);
            const bf16x8 pf = __builtin_bit_cast(bf16x8, uint4v{o0, o1, o2, o3});
            o[ti][0] = __builtin_amdgcn_mfma_f32_16x16x32_bf16(pf, va, o[ti][0], 0, 0, 0);
            o[ti][1] = __builtin_amdgcn_mfma_f32_16x16x32_bf16(pf, vb, o[ti][1], 0, 0, 0);
#endif
        }
    }

    // ---- epilogue: denominator reduce, virtual zeros, LePE, store ----
    #pragma unroll
    for (int ti = 0; ti < 2; ++ti) {
        float den = ssum[ti];
        den += __shfl_xor(den, 16);
        den += __shfl_xor(den, 32);
        den += VIRT_ * 0.0000152587890625f; // 320 * 2^-16
        const float osc = 1.0f / den;       // valid in every lane, for q = l15

#if USE_MFMA16
        // o[ti][h2] reg r = O[q=l15][cbase + h2*16 + g*4 + r] — fully lane-local
        const int qrow = (wv + ti * 14) * 16 + l15;
        const int t = qrow / 224, rr = qrow % 224;
        const int h = rr >> 2, wi = rr & 3;
        const size_t off =
            ((size_t)(((b * T_ + t) * H_ + h) * W_ + (ww * 4 + wi))) * C_ + cbase;
        #pragma unroll
        for (int h2 = 0; h2 < 2; ++h2) {
            const int co = h2 * 16 + g * 4;
            const bf16x4 lp = *(const bf16x4*)(lepe + off + co);
            f32x4 val;
            #pragma unroll
            for (int r = 0; r < 4; ++r) val[r] = o[ti][h2][r] * osc + (float)lp[r];
            *(f32x4*)(out + off + co) = val;
        }
#else
        // o[ti][j] reg r = O[q = g*4+r][hd = l15 + 16*j]
        #pragma unroll
        for (int r = 0; r < 4; ++r) {
            const float oscr = __shfl(osc, g * 4 + r);
            const int qrow = (wv + ti * 14) * 16 + g * 4 + r;
            const int t = qrow / 224, rr = qrow % 224;
            const int h = rr >> 2, wi = rr & 3;
            const size_t off =
                ((size_t)(((b * T_ + t) * H_ + h) * W_ + (ww * 4 + wi))) * C_ + cbase + l15;
            out[off]      = o[ti][0][r] * oscr + (float)lepe[off];
            out[off + 16] = o[ti][1][r] * oscr + (float)lepe[off + 16];
        }
#endif
    }
}

// ---------------------------------------------------------------------------
extern "C" void kernel_launch(void* const* d_in, const int* in_sizes, int n_in,
                              void* d_out, int out_size, void* d_ws, size_t ws_size,
                              hipStream_t stream) {
    const float* qkv = (const float*)d_in[0];
    const float* gw  = (const float*)d_in[1];
    const float* gb  = (const float*)d_in[2];
    const float* pw  = (const float*)d_in[3];
    const float* pb  = (const float*)d_in[4];

    const size_t plane = (size_t)B_ * T_ * H_ * W_ * C_; // 3,211,264
    const float* q_in = qkv;
    const float* k_in = qkv + plane;
    const float* v_in = qkv + 2 * plane;

    float* pmk_part = (float*)d_ws;                 // 4 * 57344 f32
    float* pmv_part = pmk_part + 4 * PMSTR_;        // 4 * 57344 f32
    bf16*  lepe     = (bf16*)(pmv_part + 4 * PMSTR_);
    float* outp     = (float*)d_out;

    hipLaunchKernelGGL(pre_kernel, dim3(224 + 1568), dim3(256), 0, stream,
                       k_in, v_in, pw, pb, gw, gb, pmk_part, pmv_part, lepe);
    hipLaunchKernelGGL(attn_kernel, dim3(28 * 8), dim3(896), 0, stream,
                       q_in, k_in, v_in, pmk_part, pmv_part, lepe, outp);
}